// Round 8
// baseline (2765.192 us; speedup 1.0000x reference)
//
#include <hip/hip_runtime.h>
#include <math.h>

#define HW 256
#define NPIX 65536

__device__ __forceinline__ float lrelu(float x) { return x >= 0.f ? x : 0.01f * x; }

// ---------------- conv0: gt [8,3,256,256] -> gt1 [8,1,256,256], 3x3 pad1, +bias ----------------
__global__ __launch_bounds__(256) void conv0_kernel(const float* __restrict__ gt,
                                                    const float* __restrict__ w0,
                                                    const float* __restrict__ b0,
                                                    float* __restrict__ gt1) {
  int idx = blockIdx.x * 256 + threadIdx.x;   // 8*65536 threads
  int n = idx >> 16;
  int px = idx & 65535;
  int y = px >> 8, x = px & 255;
  float acc = b0[0];
  #pragma unroll
  for (int c = 0; c < 3; ++c) {
    const float* src = gt + (size_t)(n * 3 + c) * NPIX;
    #pragma unroll
    for (int ky = 0; ky < 3; ++ky) {
      int yy = y + ky - 1;
      if (yy < 0 || yy > 255) continue;
      #pragma unroll
      for (int kx = 0; kx < 3; ++kx) {
        int xx = x + kx - 1;
        if (xx < 0 || xx > 255) continue;
        acc = fmaf(src[yy * HW + xx], w0[(c * 3 + ky) * 3 + kx], acc);
      }
    }
  }
  gt1[idx] = acc;
}

// ---------------- L1: 1 -> 16, 3x3 pad1, BN1, lrelu ----------------
__global__ __launch_bounds__(256) void conv1_kernel(const float* __restrict__ gt1,
                                                    const float* __restrict__ refs,
                                                    const float* __restrict__ w1,
                                                    const float* __restrict__ b1,
                                                    const float* __restrict__ g1,
                                                    const float* __restrict__ be1,
                                                    const float* __restrict__ m1,
                                                    const float* __restrict__ v1,
                                                    float* __restrict__ out, int i0) {
  __shared__ float sIn[34 * 34];
  __shared__ float sW[144];
  __shared__ float sScale[16], sShift[16];
  const int t = threadIdx.x;
  const int nz = blockIdx.z, n = i0 + nz;
  const int X0 = blockIdx.x * 32, Y0 = blockIdx.y * 32;
  const float* src = (n < 8) ? (gt1 + (size_t)n * NPIX) : (refs + (size_t)(n - 8) * NPIX);
  for (int id = t; id < 34 * 34; id += 256) {
    int row = id / 34, col = id - row * 34;
    int gy = Y0 + row - 1, gx = X0 + col - 1;
    float val = 0.f;
    if (gy >= 0 && gy < HW && gx >= 0 && gx < HW) val = src[gy * HW + gx];
    sIn[id] = val;
  }
  if (t < 144) sW[t] = w1[t];
  if (t < 16) {
    float inv = g1[t] / sqrtf(v1[t] + 1e-5f);
    sScale[t] = inv;
    sShift[t] = b1[t] * inv + be1[t] - m1[t] * inv;
  }
  __syncthreads();
  const int tx = t & 15, ty = t >> 4;
  const int lx = tx * 2, ly = ty * 2;
  float rin[4][4];
  #pragma unroll
  for (int r = 0; r < 4; ++r)
    #pragma unroll
    for (int c = 0; c < 4; ++c) rin[r][c] = sIn[(ly + r) * 34 + lx + c];
  #pragma unroll
  for (int oc = 0; oc < 16; ++oc) {
    float wv[9];
    #pragma unroll
    for (int k = 0; k < 9; ++k) wv[k] = sW[oc * 9 + k];
    float a[2][2] = {{0.f, 0.f}, {0.f, 0.f}};
    #pragma unroll
    for (int ky = 0; ky < 3; ++ky)
      #pragma unroll
      for (int kx = 0; kx < 3; ++kx) {
        const float wc = wv[ky * 3 + kx];
        a[0][0] = fmaf(rin[ky][kx], wc, a[0][0]);
        a[0][1] = fmaf(rin[ky][kx + 1], wc, a[0][1]);
        a[1][0] = fmaf(rin[ky + 1][kx], wc, a[1][0]);
        a[1][1] = fmaf(rin[ky + 1][kx + 1], wc, a[1][1]);
      }
    const float sc = sScale[oc], sh = sShift[oc];
    #pragma unroll
    for (int dy = 0; dy < 2; ++dy)
      #pragma unroll
      for (int dx = 0; dx < 2; ++dx) {
        int gy = Y0 + ly + dy, gx = X0 + lx + dx;
        out[(size_t)(nz * 16 + oc) * NPIX + gy * HW + gx] = lrelu(a[dy][dx] * sc + sh);
      }
  }
}

// ---------------- heavy conv v3: CIN -> 32, KxK, pad K/2, BN, lrelu ----------------
// 512 threads = 8 waves. Tile 32(x) x 16(y). Wave w owns oc [4w, 4w+4):
//  - weight addresses wave-uniform -> scalar loads; only 4x KK live SGPRs, ping-pong
//    prefetched one oc ahead so s_load latency hides under FMAs.
//  - double-buffered LDS input tile, ONE barrier per input channel.
//  - global->reg prefetch 2 channels ahead of compute.
// Lane l: 4x2 px at (col 4*(l&7), row 2*(l>>3)). acc = 4 oc x 2 x 4 = 32 regs.
template <int CIN, int K>
__global__ __launch_bounds__(512, 2) void convT3_kernel(const float* __restrict__ in,
                                                        const float* __restrict__ w,
                                                        const float* __restrict__ bias,
                                                        const float* __restrict__ gg,
                                                        const float* __restrict__ be,
                                                        const float* __restrict__ mm,
                                                        const float* __restrict__ vv_,
                                                        float* __restrict__ out) {
  constexpr int KK = K * K;
  constexpr int PAD = K / 2;
  constexpr int ROWS = 16 + K - 1;   // staged input rows
  constexpr int NIN = ROWS * 36;     // LDS floats, row stride 36
  constexpr int NQ = (NIN + 511) / 512;
  constexpr int RR = 2 + K - 1;      // per-lane input rows
  __shared__ float sIn[2][NIN];
  __shared__ float sScale[32], sShift[32];
  const int t = threadIdx.x;
  if (t < 32) {
    float inv = gg[t] / sqrtf(vv_[t] + 1e-5f);
    sScale[t] = inv;
    sShift[t] = bias[t] * inv + be[t] - mm[t] * inv;
  }
  const int X0 = blockIdx.x * 32, Y0 = blockIdx.y * 16;
  const int nz = blockIdx.z;
  const int wave = __builtin_amdgcn_readfirstlane(t >> 6);  // 0..7, wave-uniform
  const int lane = t & 63;
  const int x0l = (lane & 7) * 4, y0l = (lane >> 3) * 2;
  const int oc0 = wave * 4;
  const float* inN = in + (size_t)nz * CIN * NPIX;
  const float* wb = w + (size_t)oc0 * CIN * KK;  // uniform base

  // hoisted staging addresses + masks
  int soff[NQ];
  bool svalid[NQ];
  #pragma unroll
  for (int q = 0; q < NQ; ++q) {
    int id = t + q * 512;
    int row = id / 36, col = id - row * 36;
    int gy = Y0 + row - PAD, gx = X0 + col - PAD;
    svalid[q] = (id < NIN) && gy >= 0 && gy < HW && gx >= 0 && gx < HW && (col < 32 + 2 * PAD);
    soff[q] = gy * HW + gx;
  }

  float acc[4][2][4];
  #pragma unroll
  for (int j = 0; j < 4; ++j)
    #pragma unroll
    for (int py = 0; py < 2; ++py)
      #pragma unroll
      for (int px = 0; px < 4; ++px) acc[j][py][px] = 0.f;

  // prologue: stage ic=0, prefetch ic=1 into regs
  float vi[NQ];
  #pragma unroll
  for (int q = 0; q < NQ; ++q) vi[q] = svalid[q] ? inN[soff[q]] : 0.f;
  #pragma unroll
  for (int q = 0; q < NQ; ++q) {
    int id = t + q * 512;
    if (id < NIN) sIn[0][id] = vi[q];
  }
  #pragma unroll
  for (int q = 0; q < NQ; ++q) vi[q] = svalid[q] ? inN[NPIX + soff[q]] : 0.f;
  __syncthreads();

  int cur = 0;
  for (int ic = 0; ic < CIN; ++ic) {
    // read this channel's tile from LDS
    const float* sBase = sIn[cur];
    float rin[RR][8];
    #pragma unroll
    for (int r = 0; r < RR; ++r) {
      const float4 a4 = *reinterpret_cast<const float4*>(&sBase[(y0l + r) * 36 + x0l]);
      const float4 b4 = *reinterpret_cast<const float4*>(&sBase[(y0l + r) * 36 + x0l + 4]);
      rin[r][0] = a4.x; rin[r][1] = a4.y; rin[r][2] = a4.z; rin[r][3] = a4.w;
      rin[r][4] = b4.x; rin[r][5] = b4.y; rin[r][6] = b4.z; rin[r][7] = b4.w;
    }
    // write next channel into alternate buffer (its readers finished at the prev barrier)
    if (ic + 1 < CIN) {
      float* sNxt = sIn[cur ^ 1];
      #pragma unroll
      for (int q = 0; q < NQ; ++q) {
        int id = t + q * 512;
        if (id < NIN) sNxt[id] = vi[q];
      }
    }
    // prefetch channel ic+2 into regs; latency hides under this channel's FMAs
    if (ic + 2 < CIN) {
      const float* src = inN + (size_t)(ic + 2) * NPIX;
      #pragma unroll
      for (int q = 0; q < NQ; ++q) vi[q] = svalid[q] ? src[soff[q]] : 0.f;
    }
    // weights: scalar, ping-pong prefetched one oc ahead
    float wcur[KK], wnxt[KK];
    {
      const float* wp = wb + (size_t)ic * KK;  // oc j=0
      #pragma unroll
      for (int k = 0; k < KK; ++k) wcur[k] = wp[k];
    }
    #pragma unroll
    for (int j = 0; j < 4; ++j) {
      if (j < 3) {
        const float* wp = wb + ((size_t)(j + 1) * CIN + ic) * KK;
        #pragma unroll
        for (int k = 0; k < KK; ++k) wnxt[k] = wp[k];
      }
      #pragma unroll
      for (int ky = 0; ky < K; ++ky)
        #pragma unroll
        for (int kx = 0; kx < K; ++kx) {
          const float wc = wcur[ky * K + kx];
          #pragma unroll
          for (int py = 0; py < 2; ++py)
            #pragma unroll
            for (int px = 0; px < 4; ++px)
              acc[j][py][px] = fmaf(rin[py + ky][px + kx], wc, acc[j][py][px]);
        }
      if (j < 3) {
        #pragma unroll
        for (int k = 0; k < KK; ++k) wcur[k] = wnxt[k];
      }
    }
    __syncthreads();
    cur ^= 1;
  }

  float* outN = out + (size_t)nz * 32 * NPIX;
  #pragma unroll
  for (int j = 0; j < 4; ++j) {
    const float sc = sScale[oc0 + j], sh = sShift[oc0 + j];
    #pragma unroll
    for (int py = 0; py < 2; ++py) {
      float4 o;
      o.x = lrelu(acc[j][py][0] * sc + sh);
      o.y = lrelu(acc[j][py][1] * sc + sh);
      o.z = lrelu(acc[j][py][2] * sc + sh);
      o.w = lrelu(acc[j][py][3] * sc + sh);
      *reinterpret_cast<float4*>(
          &outN[(size_t)(oc0 + j) * NPIX + (Y0 + y0l + py) * HW + X0 + x0l]) = o;
    }
  }
}

// ---------------- L4: 32 -> 1, 3x3 pad1, BN4, +residual, lrelu -> feat [40][NPIX] ----------------
// double-buffered LDS, one barrier per channel, hoisted addresses, scalar weights.
__global__ __launch_bounds__(256) void conv4_kernel(const float* __restrict__ in,
                                                    const float* __restrict__ gt1,
                                                    const float* __restrict__ refs,
                                                    const float* __restrict__ w4,
                                                    const float* __restrict__ b4,
                                                    const float* __restrict__ g4,
                                                    const float* __restrict__ be4,
                                                    const float* __restrict__ m4,
                                                    const float* __restrict__ v4,
                                                    float* __restrict__ feat, int i0) {
  __shared__ float sIn[2][34 * 34];
  const int t = threadIdx.x;
  const int nz = blockIdx.z, n = i0 + nz;
  const int X0 = blockIdx.x * 32, Y0 = blockIdx.y * 32;
  const int tx = t & 15, ty = t >> 4;
  const int lx = tx * 2, ly = ty * 2;
  const float* inN = in + (size_t)nz * 32 * NPIX;

  int soff[5];
  bool svalid[5];
  #pragma unroll
  for (int q = 0; q < 5; ++q) {
    int id = t + q * 256;
    int row = id / 34, col = id - row * 34;
    int gy = Y0 + row - 1, gx = X0 + col - 1;
    svalid[q] = (id < 34 * 34) && gy >= 0 && gy < HW && gx >= 0 && gx < HW;
    soff[q] = gy * HW + gx;
  }

  float a[2][2] = {{0.f, 0.f}, {0.f, 0.f}};
  float vi[5];
  #pragma unroll
  for (int q = 0; q < 5; ++q) vi[q] = svalid[q] ? inN[soff[q]] : 0.f;
  #pragma unroll
  for (int q = 0; q < 5; ++q) {
    int id = t + q * 256;
    if (id < 34 * 34) sIn[0][id] = vi[q];
  }
  #pragma unroll
  for (int q = 0; q < 5; ++q) vi[q] = svalid[q] ? inN[NPIX + soff[q]] : 0.f;
  __syncthreads();

  int cur = 0;
  for (int ic = 0; ic < 32; ++ic) {
    const float* sBase = sIn[cur];
    float rin[4][4];
    #pragma unroll
    for (int r = 0; r < 4; ++r) {
      const float2 p0 = *reinterpret_cast<const float2*>(&sBase[(ly + r) * 34 + lx]);
      const float2 p1 = *reinterpret_cast<const float2*>(&sBase[(ly + r) * 34 + lx + 2]);
      rin[r][0] = p0.x; rin[r][1] = p0.y; rin[r][2] = p1.x; rin[r][3] = p1.y;
    }
    if (ic + 1 < 32) {
      float* sNxt = sIn[cur ^ 1];
      #pragma unroll
      for (int q = 0; q < 5; ++q) {
        int id = t + q * 256;
        if (id < 34 * 34) sNxt[id] = vi[q];
      }
    }
    if (ic + 2 < 32) {
      const float* src = inN + (size_t)(ic + 2) * NPIX;
      #pragma unroll
      for (int q = 0; q < 5; ++q) vi[q] = svalid[q] ? src[soff[q]] : 0.f;
    }
    const float* wp = w4 + ic * 9;  // uniform -> s_load
    float wv[9];
    #pragma unroll
    for (int k = 0; k < 9; ++k) wv[k] = wp[k];
    #pragma unroll
    for (int ky = 0; ky < 3; ++ky)
      #pragma unroll
      for (int kx = 0; kx < 3; ++kx) {
        const float wc = wv[ky * 3 + kx];
        a[0][0] = fmaf(rin[ky][kx], wc, a[0][0]);
        a[0][1] = fmaf(rin[ky][kx + 1], wc, a[0][1]);
        a[1][0] = fmaf(rin[ky + 1][kx], wc, a[1][0]);
        a[1][1] = fmaf(rin[ky + 1][kx + 1], wc, a[1][1]);
      }
    __syncthreads();
    cur ^= 1;
  }
  const float inv = g4[0] / sqrtf(v4[0] + 1e-5f);
  const float sh = b4[0] * inv + be4[0] - m4[0] * inv;
  const float* res = (n < 8) ? (gt1 + (size_t)n * NPIX) : (refs + (size_t)(n - 8) * NPIX);
  #pragma unroll
  for (int dy = 0; dy < 2; ++dy)
    #pragma unroll
    for (int dx = 0; dx < 2; ++dx) {
      int px = (Y0 + ly + dy) * HW + X0 + lx + dx;
      float val = a[dy][dx] * inv + sh + res[px];
      feat[(size_t)n * NPIX + px] = lrelu(val);
    }
}

// ---------------- final: diff/min/max/norm/threshold/argmax/collage ----------------
__global__ __launch_bounds__(256) void final_kernel(const float* __restrict__ feat,
                                                    float* __restrict__ outD) {
  int idx = blockIdx.x * 256 + threadIdx.x;  // 8*65536
  int b = idx >> 16, px = idx & 65535;
  float gv = feat[(size_t)b * NPIX + px];
  float tv[4];
  float mn = 1e30f, mx = -1e30f;
  #pragma unroll
  for (int r = 0; r < 4; ++r) {
    float rv = feat[(size_t)(8 + b * 4 + r) * NPIX + px];
    tv[r] = fabsf(gv - rv);
    mn = fminf(mn, tv[r]);
    mx = fmaxf(mx, tv[r]);
  }
  const float denom = mx - mn + 1e-8f;
  float d[4];
  #pragma unroll
  for (int r = 0; r < 4; ++r) {
    float nrm = (tv[r] - mn) / denom;
    nrm = fminf(fmaxf(nrm, 0.1f), 1.0f);
    d[r] = nrm > 0.5f ? nrm : 0.f;
    outD[(size_t)(b * 4 + r) * NPIX + px] = d[r];
  }
  int best = 0;
  float bv = d[0];
  #pragma unroll
  for (int r = 1; r < 4; ++r)
    if (d[r] > bv) { bv = d[r]; best = r; }
  outD[(size_t)32 * NPIX + (size_t)b * NPIX + px] =
      feat[(size_t)(8 + b * 4 + best) * NPIX + px];
}

extern "C" void kernel_launch(void* const* d_in, const int* in_sizes, int n_in,
                              void* d_out, int out_size, void* d_ws, size_t ws_size,
                              hipStream_t stream) {
  const float* gt   = (const float*)d_in[0];
  const float* refs = (const float*)d_in[1];
  const float* w0 = (const float*)d_in[2];
  const float* b0 = (const float*)d_in[3];
  const float* w1 = (const float*)d_in[4];
  const float* b1 = (const float*)d_in[5];
  const float* g1 = (const float*)d_in[6];
  const float* be1 = (const float*)d_in[7];
  const float* m1 = (const float*)d_in[8];
  const float* v1 = (const float*)d_in[9];
  const float* w2 = (const float*)d_in[10];
  const float* b2 = (const float*)d_in[11];
  const float* g2 = (const float*)d_in[12];
  const float* be2 = (const float*)d_in[13];
  const float* m2 = (const float*)d_in[14];
  const float* v2 = (const float*)d_in[15];
  const float* w3 = (const float*)d_in[16];
  const float* b3 = (const float*)d_in[17];
  const float* g3 = (const float*)d_in[18];
  const float* be3 = (const float*)d_in[19];
  const float* m3 = (const float*)d_in[20];
  const float* v3 = (const float*)d_in[21];
  const float* w4 = (const float*)d_in[22];
  const float* b4 = (const float*)d_in[23];
  const float* g4 = (const float*)d_in[24];
  const float* be4 = (const float*)d_in[25];
  const float* m4 = (const float*)d_in[26];
  const float* v4 = (const float*)d_in[27];

  float* ws = (float*)d_ws;
  float* gt1  = ws;                      // 8 * NPIX
  float* feat = gt1 + (size_t)8 * NPIX;  // 40 * NPIX
  float* bufBase = feat + (size_t)40 * NPIX;

  size_t fixedBytes = (size_t)(8 + 40) * NPIX * sizeof(float);
  size_t avail = (ws_size > fixedBytes) ? (ws_size - fixedBytes) : 0;
  size_t perImg = (size_t)2 * 32 * NPIX * sizeof(float);  // bufA + bufB per image
  int maxC = (int)(avail / perImg);
  static const int divs[8] = {40, 20, 10, 8, 5, 4, 2, 1};
  int chunk = 1;
  for (int i = 0; i < 8; ++i)
    if (divs[i] <= maxC) { chunk = divs[i]; break; }

  float* bufA = bufBase;
  float* bufB = bufA + (size_t)chunk * 32 * NPIX;

  conv0_kernel<<<2048, 256, 0, stream>>>(gt, w0, b0, gt1);

  for (int i0 = 0; i0 < 40; i0 += chunk) {
    conv1_kernel<<<dim3(8, 8, chunk), 256, 0, stream>>>(gt1, refs, w1, b1, g1, be1, m1, v1,
                                                        bufA, i0);
    convT3_kernel<16, 3><<<dim3(8, 16, chunk), 512, 0, stream>>>(bufA, w2, b2, g2, be2, m2, v2,
                                                                 bufB);
    convT3_kernel<32, 5><<<dim3(8, 16, chunk), 512, 0, stream>>>(bufB, w3, b3, g3, be3, m3, v3,
                                                                 bufA);
    conv4_kernel<<<dim3(8, 8, chunk), 256, 0, stream>>>(bufA, gt1, refs, w4, b4, g4, be4, m4,
                                                        v4, feat, i0);
  }

  final_kernel<<<2048, 256, 0, stream>>>(feat, (float*)d_out);
}

// Round 13
// 2473.503 us; speedup vs baseline: 1.1179x; 1.1179x over previous
//
#include <hip/hip_runtime.h>
#include <math.h>

#define HW 256
#define NPIX 65536

__device__ __forceinline__ float lrelu(float x) { return x >= 0.f ? x : 0.01f * x; }

// ---------------- conv0: gt [8,3,256,256] -> gt1 [8,1,256,256], 3x3 pad1, +bias ----------------
__global__ __launch_bounds__(256) void conv0_kernel(const float* __restrict__ gt,
                                                    const float* __restrict__ w0,
                                                    const float* __restrict__ b0,
                                                    float* __restrict__ gt1) {
  int idx = blockIdx.x * 256 + threadIdx.x;   // 8*65536 threads
  int n = idx >> 16;
  int px = idx & 65535;
  int y = px >> 8, x = px & 255;
  float acc = b0[0];
  #pragma unroll
  for (int c = 0; c < 3; ++c) {
    const float* src = gt + (size_t)(n * 3 + c) * NPIX;
    #pragma unroll
    for (int ky = 0; ky < 3; ++ky) {
      int yy = y + ky - 1;
      if (yy < 0 || yy > 255) continue;
      #pragma unroll
      for (int kx = 0; kx < 3; ++kx) {
        int xx = x + kx - 1;
        if (xx < 0 || xx > 255) continue;
        acc = fmaf(src[yy * HW + xx], w0[(c * 3 + ky) * 3 + kx], acc);
      }
    }
  }
  gt1[idx] = acc;
}

// ---------------- L1: 1 -> 16, 3x3 pad1, BN1, lrelu ----------------
__global__ __launch_bounds__(256) void conv1_kernel(const float* __restrict__ gt1,
                                                    const float* __restrict__ refs,
                                                    const float* __restrict__ w1,
                                                    const float* __restrict__ b1,
                                                    const float* __restrict__ g1,
                                                    const float* __restrict__ be1,
                                                    const float* __restrict__ m1,
                                                    const float* __restrict__ v1,
                                                    float* __restrict__ out, int i0) {
  __shared__ float sIn[34 * 34];
  __shared__ float sW[144];
  __shared__ float sScale[16], sShift[16];
  const int t = threadIdx.x;
  const int nz = blockIdx.z, n = i0 + nz;
  const int X0 = blockIdx.x * 32, Y0 = blockIdx.y * 32;
  const float* src = (n < 8) ? (gt1 + (size_t)n * NPIX) : (refs + (size_t)(n - 8) * NPIX);
  for (int id = t; id < 34 * 34; id += 256) {
    int row = id / 34, col = id - row * 34;
    int gy = Y0 + row - 1, gx = X0 + col - 1;
    float val = 0.f;
    if (gy >= 0 && gy < HW && gx >= 0 && gx < HW) val = src[gy * HW + gx];
    sIn[id] = val;
  }
  if (t < 144) sW[t] = w1[t];
  if (t < 16) {
    float inv = g1[t] / sqrtf(v1[t] + 1e-5f);
    sScale[t] = inv;
    sShift[t] = b1[t] * inv + be1[t] - m1[t] * inv;
  }
  __syncthreads();
  const int tx = t & 15, ty = t >> 4;
  const int lx = tx * 2, ly = ty * 2;
  float rin[4][4];
  #pragma unroll
  for (int r = 0; r < 4; ++r)
    #pragma unroll
    for (int c = 0; c < 4; ++c) rin[r][c] = sIn[(ly + r) * 34 + lx + c];
  #pragma unroll
  for (int oc = 0; oc < 16; ++oc) {
    float wv[9];
    #pragma unroll
    for (int k = 0; k < 9; ++k) wv[k] = sW[oc * 9 + k];
    float a[2][2] = {{0.f, 0.f}, {0.f, 0.f}};
    #pragma unroll
    for (int ky = 0; ky < 3; ++ky)
      #pragma unroll
      for (int kx = 0; kx < 3; ++kx) {
        const float wc = wv[ky * 3 + kx];
        a[0][0] = fmaf(rin[ky][kx], wc, a[0][0]);
        a[0][1] = fmaf(rin[ky][kx + 1], wc, a[0][1]);
        a[1][0] = fmaf(rin[ky + 1][kx], wc, a[1][0]);
        a[1][1] = fmaf(rin[ky + 1][kx + 1], wc, a[1][1]);
      }
    const float sc = sScale[oc], sh = sShift[oc];
    #pragma unroll
    for (int dy = 0; dy < 2; ++dy)
      #pragma unroll
      for (int dx = 0; dx < 2; ++dx) {
        int gy = Y0 + ly + dy, gx = X0 + lx + dx;
        out[(size_t)(nz * 16 + oc) * NPIX + gy * HW + gx] = lrelu(a[dy][dx] * sc + sh);
      }
  }
}

// ---------------- heavy conv v4: CIN -> 32, KxK, pad K/2, BN, lrelu ----------------
// Proven convT2 structure (R4: 360us, VALUBusy 77%): 256 thr = 4 waves,
// wave owns 8 oc (scalar s_load weights), lane = 4x2 px of the 32x16 tile.
// ONE change vs convT2: ic-loop unrolled by 2 -> stage BOTH channel tiles, one
// barrier pair per TWO channels (halves barrier count; 2x FMA per phase).
template <int CIN, int K>
__global__ __launch_bounds__(256, 2) void convT4_kernel(const float* __restrict__ in,
                                                        const float* __restrict__ w,
                                                        const float* __restrict__ bias,
                                                        const float* __restrict__ gg,
                                                        const float* __restrict__ be,
                                                        const float* __restrict__ mm,
                                                        const float* __restrict__ vv_,
                                                        float* __restrict__ out) {
  constexpr int KK = K * K;
  constexpr int PAD = K / 2;
  constexpr int ROWS = 16 + K - 1;        // staged input rows
  constexpr int NIN = ROWS * 36;          // LDS floats per tile, row stride 36
  constexpr int NQ = (NIN + 255) / 256;   // 3 for K=3 and K=5
  constexpr int RR = 2 + K - 1;           // per-lane input rows
  __shared__ float sIn[2][NIN];
  __shared__ float sScale[32], sShift[32];
  const int t = threadIdx.x;
  if (t < 32) {
    float inv = gg[t] / sqrtf(vv_[t] + 1e-5f);
    sScale[t] = inv;
    sShift[t] = bias[t] * inv + be[t] - mm[t] * inv;
  }
  const int X0 = blockIdx.x * 32, Y0 = blockIdx.y * 16;
  const int nz = blockIdx.z;
  const int wave = __builtin_amdgcn_readfirstlane(t >> 6);  // 0..3, wave-uniform
  const int lane = t & 63;
  const int x0l = (lane & 7) * 4, y0l = (lane >> 3) * 2;
  const int oc0 = wave * 8;
  const float* inN = in + (size_t)nz * CIN * NPIX;
  const float* wb = w + (size_t)oc0 * CIN * KK;  // uniform base -> s_load

  // hoisted staging addresses + masks
  int soff[NQ];
  bool svalid[NQ];
  #pragma unroll
  for (int q = 0; q < NQ; ++q) {
    int id = t + q * 256;
    int row = id / 36, col = id - row * 36;
    int gy = Y0 + row - PAD, gx = X0 + col - PAD;
    svalid[q] = (id < NIN) && gy >= 0 && gy < HW && gx >= 0 && gx < HW && (col < 32 + 2 * PAD);
    soff[q] = gy * HW + gx;
  }

  float acc[8][2][4];
  #pragma unroll
  for (int j = 0; j < 8; ++j)
    #pragma unroll
    for (int py = 0; py < 2; ++py)
      #pragma unroll
      for (int px = 0; px < 4; ++px) acc[j][py][px] = 0.f;

  // prologue: prefetch channels 0 and 1 into regs
  float vi0[NQ], vi1[NQ];
  #pragma unroll
  for (int q = 0; q < NQ; ++q) vi0[q] = svalid[q] ? inN[soff[q]] : 0.f;
  #pragma unroll
  for (int q = 0; q < NQ; ++q) vi1[q] = svalid[q] ? inN[NPIX + soff[q]] : 0.f;

  for (int ic = 0; ic < CIN; ic += 2) {
    // write both staged tiles (prev barrier guarantees readers are done)
    #pragma unroll
    for (int q = 0; q < NQ; ++q) {
      int id = t + q * 256;
      if (id < NIN) sIn[0][id] = vi0[q];
    }
    #pragma unroll
    for (int q = 0; q < NQ; ++q) {
      int id = t + q * 256;
      if (id < NIN) sIn[1][id] = vi1[q];
    }
    __syncthreads();
    // prefetch channels ic+2, ic+3; latency hides under ~6400 FMA cycles
    if (ic + 2 < CIN) {
      const float* s0 = inN + (size_t)(ic + 2) * NPIX;
      const float* s1 = inN + (size_t)(ic + 3) * NPIX;
      #pragma unroll
      for (int q = 0; q < NQ; ++q) vi0[q] = svalid[q] ? s0[soff[q]] : 0.f;
      #pragma unroll
      for (int q = 0; q < NQ; ++q) vi1[q] = svalid[q] ? s1[soff[q]] : 0.f;
    }
    // compute both halves
    #pragma unroll
    for (int h = 0; h < 2; ++h) {
      const float* sBase = sIn[h];
      float rin[RR][8];
      #pragma unroll
      for (int r = 0; r < RR; ++r) {
        const float4 a4 = *reinterpret_cast<const float4*>(&sBase[(y0l + r) * 36 + x0l]);
        const float4 b4 = *reinterpret_cast<const float4*>(&sBase[(y0l + r) * 36 + x0l + 4]);
        rin[r][0] = a4.x; rin[r][1] = a4.y; rin[r][2] = a4.z; rin[r][3] = a4.w;
        rin[r][4] = b4.x; rin[r][5] = b4.y; rin[r][6] = b4.z; rin[r][7] = b4.w;
      }
      #pragma unroll
      for (int j = 0; j < 8; ++j) {
        const float* wp = wb + ((size_t)j * CIN + (ic + h)) * KK;  // uniform -> s_load
        float wr[KK];
        #pragma unroll
        for (int k = 0; k < KK; ++k) wr[k] = wp[k];
        #pragma unroll
        for (int ky = 0; ky < K; ++ky)
          #pragma unroll
          for (int kx = 0; kx < K; ++kx) {
            const float wc = wr[ky * K + kx];
            #pragma unroll
            for (int py = 0; py < 2; ++py)
              #pragma unroll
              for (int px = 0; px < 4; ++px)
                acc[j][py][px] = fmaf(rin[py + ky][px + kx], wc, acc[j][py][px]);
          }
      }
    }
    __syncthreads();
  }

  float* outN = out + (size_t)nz * 32 * NPIX;
  #pragma unroll
  for (int j = 0; j < 8; ++j) {
    const float sc = sScale[oc0 + j], sh = sShift[oc0 + j];
    #pragma unroll
    for (int py = 0; py < 2; ++py) {
      float4 o;
      o.x = lrelu(acc[j][py][0] * sc + sh);
      o.y = lrelu(acc[j][py][1] * sc + sh);
      o.z = lrelu(acc[j][py][2] * sc + sh);
      o.w = lrelu(acc[j][py][3] * sc + sh);
      *reinterpret_cast<float4*>(
          &outN[(size_t)(oc0 + j) * NPIX + (Y0 + y0l + py) * HW + X0 + x0l]) = o;
    }
  }
}

// ---------------- L4: 32 -> 1, 3x3 pad1, BN4, +residual, lrelu -> feat [40][NPIX] ----------------
// double-buffered LDS, one barrier per channel, hoisted addresses, scalar weights.
__global__ __launch_bounds__(256) void conv4_kernel(const float* __restrict__ in,
                                                    const float* __restrict__ gt1,
                                                    const float* __restrict__ refs,
                                                    const float* __restrict__ w4,
                                                    const float* __restrict__ b4,
                                                    const float* __restrict__ g4,
                                                    const float* __restrict__ be4,
                                                    const float* __restrict__ m4,
                                                    const float* __restrict__ v4,
                                                    float* __restrict__ feat, int i0) {
  __shared__ float sIn[2][34 * 34];
  const int t = threadIdx.x;
  const int nz = blockIdx.z, n = i0 + nz;
  const int X0 = blockIdx.x * 32, Y0 = blockIdx.y * 32;
  const int tx = t & 15, ty = t >> 4;
  const int lx = tx * 2, ly = ty * 2;
  const float* inN = in + (size_t)nz * 32 * NPIX;

  int soff[5];
  bool svalid[5];
  #pragma unroll
  for (int q = 0; q < 5; ++q) {
    int id = t + q * 256;
    int row = id / 34, col = id - row * 34;
    int gy = Y0 + row - 1, gx = X0 + col - 1;
    svalid[q] = (id < 34 * 34) && gy >= 0 && gy < HW && gx >= 0 && gx < HW;
    soff[q] = gy * HW + gx;
  }

  float a[2][2] = {{0.f, 0.f}, {0.f, 0.f}};
  float vi[5];
  #pragma unroll
  for (int q = 0; q < 5; ++q) vi[q] = svalid[q] ? inN[soff[q]] : 0.f;
  #pragma unroll
  for (int q = 0; q < 5; ++q) {
    int id = t + q * 256;
    if (id < 34 * 34) sIn[0][id] = vi[q];
  }
  #pragma unroll
  for (int q = 0; q < 5; ++q) vi[q] = svalid[q] ? inN[NPIX + soff[q]] : 0.f;
  __syncthreads();

  int cur = 0;
  for (int ic = 0; ic < 32; ++ic) {
    const float* sBase = sIn[cur];
    float rin[4][4];
    #pragma unroll
    for (int r = 0; r < 4; ++r) {
      const float2 p0 = *reinterpret_cast<const float2*>(&sBase[(ly + r) * 34 + lx]);
      const float2 p1 = *reinterpret_cast<const float2*>(&sBase[(ly + r) * 34 + lx + 2]);
      rin[r][0] = p0.x; rin[r][1] = p0.y; rin[r][2] = p1.x; rin[r][3] = p1.y;
    }
    if (ic + 1 < 32) {
      float* sNxt = sIn[cur ^ 1];
      #pragma unroll
      for (int q = 0; q < 5; ++q) {
        int id = t + q * 256;
        if (id < 34 * 34) sNxt[id] = vi[q];
      }
    }
    if (ic + 2 < 32) {
      const float* src = inN + (size_t)(ic + 2) * NPIX;
      #pragma unroll
      for (int q = 0; q < 5; ++q) vi[q] = svalid[q] ? src[soff[q]] : 0.f;
    }
    const float* wp = w4 + ic * 9;  // uniform -> s_load
    float wv[9];
    #pragma unroll
    for (int k = 0; k < 9; ++k) wv[k] = wp[k];
    #pragma unroll
    for (int ky = 0; ky < 3; ++ky)
      #pragma unroll
      for (int kx = 0; kx < 3; ++kx) {
        const float wc = wv[ky * 3 + kx];
        a[0][0] = fmaf(rin[ky][kx], wc, a[0][0]);
        a[0][1] = fmaf(rin[ky][kx + 1], wc, a[0][1]);
        a[1][0] = fmaf(rin[ky + 1][kx], wc, a[1][0]);
        a[1][1] = fmaf(rin[ky + 1][kx + 1], wc, a[1][1]);
      }
    __syncthreads();
    cur ^= 1;
  }
  const float inv = g4[0] / sqrtf(v4[0] + 1e-5f);
  const float sh = b4[0] * inv + be4[0] - m4[0] * inv;
  const float* res = (n < 8) ? (gt1 + (size_t)n * NPIX) : (refs + (size_t)(n - 8) * NPIX);
  #pragma unroll
  for (int dy = 0; dy < 2; ++dy)
    #pragma unroll
    for (int dx = 0; dx < 2; ++dx) {
      int px = (Y0 + ly + dy) * HW + X0 + lx + dx;
      float val = a[dy][dx] * inv + sh + res[px];
      feat[(size_t)n * NPIX + px] = lrelu(val);
    }
}

// ---------------- final: diff/min/max/norm/threshold/argmax/collage ----------------
__global__ __launch_bounds__(256) void final_kernel(const float* __restrict__ feat,
                                                    float* __restrict__ outD) {
  int idx = blockIdx.x * 256 + threadIdx.x;  // 8*65536
  int b = idx >> 16, px = idx & 65535;
  float gv = feat[(size_t)b * NPIX + px];
  float tv[4];
  float mn = 1e30f, mx = -1e30f;
  #pragma unroll
  for (int r = 0; r < 4; ++r) {
    float rv = feat[(size_t)(8 + b * 4 + r) * NPIX + px];
    tv[r] = fabsf(gv - rv);
    mn = fminf(mn, tv[r]);
    mx = fmaxf(mx, tv[r]);
  }
  const float denom = mx - mn + 1e-8f;
  float d[4];
  #pragma unroll
  for (int r = 0; r < 4; ++r) {
    float nrm = (tv[r] - mn) / denom;
    nrm = fminf(fmaxf(nrm, 0.1f), 1.0f);
    d[r] = nrm > 0.5f ? nrm : 0.f;
    outD[(size_t)(b * 4 + r) * NPIX + px] = d[r];
  }
  int best = 0;
  float bv = d[0];
  #pragma unroll
  for (int r = 1; r < 4; ++r)
    if (d[r] > bv) { bv = d[r]; best = r; }
  outD[(size_t)32 * NPIX + (size_t)b * NPIX + px] =
      feat[(size_t)(8 + b * 4 + best) * NPIX + px];
}

extern "C" void kernel_launch(void* const* d_in, const int* in_sizes, int n_in,
                              void* d_out, int out_size, void* d_ws, size_t ws_size,
                              hipStream_t stream) {
  const float* gt   = (const float*)d_in[0];
  const float* refs = (const float*)d_in[1];
  const float* w0 = (const float*)d_in[2];
  const float* b0 = (const float*)d_in[3];
  const float* w1 = (const float*)d_in[4];
  const float* b1 = (const float*)d_in[5];
  const float* g1 = (const float*)d_in[6];
  const float* be1 = (const float*)d_in[7];
  const float* m1 = (const float*)d_in[8];
  const float* v1 = (const float*)d_in[9];
  const float* w2 = (const float*)d_in[10];
  const float* b2 = (const float*)d_in[11];
  const float* g2 = (const float*)d_in[12];
  const float* be2 = (const float*)d_in[13];
  const float* m2 = (const float*)d_in[14];
  const float* v2 = (const float*)d_in[15];
  const float* w3 = (const float*)d_in[16];
  const float* b3 = (const float*)d_in[17];
  const float* g3 = (const float*)d_in[18];
  const float* be3 = (const float*)d_in[19];
  const float* m3 = (const float*)d_in[20];
  const float* v3 = (const float*)d_in[21];
  const float* w4 = (const float*)d_in[22];
  const float* b4 = (const float*)d_in[23];
  const float* g4 = (const float*)d_in[24];
  const float* be4 = (const float*)d_in[25];
  const float* m4 = (const float*)d_in[26];
  const float* v4 = (const float*)d_in[27];

  float* ws = (float*)d_ws;
  float* gt1  = ws;                      // 8 * NPIX
  float* feat = gt1 + (size_t)8 * NPIX;  // 40 * NPIX
  float* bufBase = feat + (size_t)40 * NPIX;

  size_t fixedBytes = (size_t)(8 + 40) * NPIX * sizeof(float);
  size_t avail = (ws_size > fixedBytes) ? (ws_size - fixedBytes) : 0;
  size_t perImg = (size_t)2 * 32 * NPIX * sizeof(float);  // bufA + bufB per image
  int maxC = (int)(avail / perImg);
  static const int divs[8] = {40, 20, 10, 8, 5, 4, 2, 1};
  int chunk = 1;
  for (int i = 0; i < 8; ++i)
    if (divs[i] <= maxC) { chunk = divs[i]; break; }

  float* bufA = bufBase;
  float* bufB = bufA + (size_t)chunk * 32 * NPIX;

  conv0_kernel<<<2048, 256, 0, stream>>>(gt, w0, b0, gt1);

  for (int i0 = 0; i0 < 40; i0 += chunk) {
    conv1_kernel<<<dim3(8, 8, chunk), 256, 0, stream>>>(gt1, refs, w1, b1, g1, be1, m1, v1,
                                                        bufA, i0);
    convT4_kernel<16, 3><<<dim3(8, 16, chunk), 256, 0, stream>>>(bufA, w2, b2, g2, be2, m2, v2,
                                                                 bufB);
    convT4_kernel<32, 5><<<dim3(8, 16, chunk), 256, 0, stream>>>(bufB, w3, b3, g3, be3, m3, v3,
                                                                 bufA);
    conv4_kernel<<<dim3(8, 8, chunk), 256, 0, stream>>>(bufA, gt1, refs, w4, b4, g4, be4, m4,
                                                        v4, feat, i0);
  }

  final_kernel<<<2048, 256, 0, stream>>>(feat, (float*)d_out);
}

// Round 14
// 1887.927 us; speedup vs baseline: 1.4647x; 1.3102x over previous
//
#include <hip/hip_runtime.h>
#include <math.h>

#define HW 256
#define NPIX 65536

__device__ __forceinline__ float lrelu(float x) { return x >= 0.f ? x : 0.01f * x; }

// ---------------- conv0: gt [8,3,256,256] -> gt1 [8,1,256,256], 3x3 pad1, +bias ----------------
__global__ __launch_bounds__(256) void conv0_kernel(const float* __restrict__ gt,
                                                    const float* __restrict__ w0,
                                                    const float* __restrict__ b0,
                                                    float* __restrict__ gt1) {
  int idx = blockIdx.x * 256 + threadIdx.x;   // 8*65536 threads
  int n = idx >> 16;
  int px = idx & 65535;
  int y = px >> 8, x = px & 255;
  float acc = b0[0];
  #pragma unroll
  for (int c = 0; c < 3; ++c) {
    const float* src = gt + (size_t)(n * 3 + c) * NPIX;
    #pragma unroll
    for (int ky = 0; ky < 3; ++ky) {
      int yy = y + ky - 1;
      if (yy < 0 || yy > 255) continue;
      #pragma unroll
      for (int kx = 0; kx < 3; ++kx) {
        int xx = x + kx - 1;
        if (xx < 0 || xx > 255) continue;
        acc = fmaf(src[yy * HW + xx], w0[(c * 3 + ky) * 3 + kx], acc);
      }
    }
  }
  gt1[idx] = acc;
}

// ---------------- L1: 1 -> 16, 3x3 pad1, BN1, lrelu ----------------
__global__ __launch_bounds__(256) void conv1_kernel(const float* __restrict__ gt1,
                                                    const float* __restrict__ refs,
                                                    const float* __restrict__ w1,
                                                    const float* __restrict__ b1,
                                                    const float* __restrict__ g1,
                                                    const float* __restrict__ be1,
                                                    const float* __restrict__ m1,
                                                    const float* __restrict__ v1,
                                                    float* __restrict__ out, int i0) {
  __shared__ float sIn[34 * 34];
  __shared__ float sW[144];
  __shared__ float sScale[16], sShift[16];
  const int t = threadIdx.x;
  const int nz = blockIdx.z, n = i0 + nz;
  const int X0 = blockIdx.x * 32, Y0 = blockIdx.y * 32;
  const float* src = (n < 8) ? (gt1 + (size_t)n * NPIX) : (refs + (size_t)(n - 8) * NPIX);
  for (int id = t; id < 34 * 34; id += 256) {
    int row = id / 34, col = id - row * 34;
    int gy = Y0 + row - 1, gx = X0 + col - 1;
    float val = 0.f;
    if (gy >= 0 && gy < HW && gx >= 0 && gx < HW) val = src[gy * HW + gx];
    sIn[id] = val;
  }
  if (t < 144) sW[t] = w1[t];
  if (t < 16) {
    float inv = g1[t] / sqrtf(v1[t] + 1e-5f);
    sScale[t] = inv;
    sShift[t] = b1[t] * inv + be1[t] - m1[t] * inv;
  }
  __syncthreads();
  const int tx = t & 15, ty = t >> 4;
  const int lx = tx * 2, ly = ty * 2;
  float rin[4][4];
  #pragma unroll
  for (int r = 0; r < 4; ++r)
    #pragma unroll
    for (int c = 0; c < 4; ++c) rin[r][c] = sIn[(ly + r) * 34 + lx + c];
  #pragma unroll
  for (int oc = 0; oc < 16; ++oc) {
    float wv[9];
    #pragma unroll
    for (int k = 0; k < 9; ++k) wv[k] = sW[oc * 9 + k];
    float a[2][2] = {{0.f, 0.f}, {0.f, 0.f}};
    #pragma unroll
    for (int ky = 0; ky < 3; ++ky)
      #pragma unroll
      for (int kx = 0; kx < 3; ++kx) {
        const float wc = wv[ky * 3 + kx];
        a[0][0] = fmaf(rin[ky][kx], wc, a[0][0]);
        a[0][1] = fmaf(rin[ky][kx + 1], wc, a[0][1]);
        a[1][0] = fmaf(rin[ky + 1][kx], wc, a[1][0]);
        a[1][1] = fmaf(rin[ky + 1][kx + 1], wc, a[1][1]);
      }
    const float sc = sScale[oc], sh = sShift[oc];
    #pragma unroll
    for (int dy = 0; dy < 2; ++dy)
      #pragma unroll
      for (int dx = 0; dx < 2; ++dx) {
        int gy = Y0 + ly + dy, gx = X0 + lx + dx;
        out[(size_t)(nz * 16 + oc) * NPIX + gy * HW + gx] = lrelu(a[dy][dx] * sc + sh);
      }
  }
}

// ---------------- heavy conv v5: CIN -> 32, KxK, pad K/2, BN, lrelu ----------------
// EXACT convT2 structure (R4: 360us, VALU 77%, best measured): 256 thr = 4 waves,
// wave owns 8 oc (scalar s_load weights), lane = 4x2 px of the 32x16 tile,
// per-ic body of 1600 FMAs (I-cache safe; convT4's 2x body regressed).
// ONE change: double-buffered LDS tile -> ONE barrier per ic instead of two.
// Iter ic writes buf[(ic+1)&1], reads buf[ic&1]; end-of-iter barrier orders both
// hazards (mechanism already validated in conv4_kernel since R8).
template <int CIN, int K>
__global__ __launch_bounds__(256, 2) void convT5_kernel(const float* __restrict__ in,
                                                        const float* __restrict__ w,
                                                        const float* __restrict__ bias,
                                                        const float* __restrict__ gg,
                                                        const float* __restrict__ be,
                                                        const float* __restrict__ mm,
                                                        const float* __restrict__ vv_,
                                                        float* __restrict__ out) {
  constexpr int KK = K * K;
  constexpr int PAD = K / 2;
  constexpr int ROWS = 16 + K - 1;        // staged input rows
  constexpr int NIN = ROWS * 36;          // LDS floats per tile, row stride 36
  constexpr int NQ = (NIN + 255) / 256;   // 3 for K=3 and K=5
  constexpr int RR = 2 + K - 1;           // per-lane input rows
  __shared__ float sIn[2][NIN];
  __shared__ float sScale[32], sShift[32];
  const int t = threadIdx.x;
  if (t < 32) {
    float inv = gg[t] / sqrtf(vv_[t] + 1e-5f);
    sScale[t] = inv;
    sShift[t] = bias[t] * inv + be[t] - mm[t] * inv;
  }
  const int X0 = blockIdx.x * 32, Y0 = blockIdx.y * 16;
  const int nz = blockIdx.z;
  const int wave = __builtin_amdgcn_readfirstlane(t >> 6);  // 0..3, wave-uniform
  const int lane = t & 63;
  const int x0l = (lane & 7) * 4, y0l = (lane >> 3) * 2;
  const int oc0 = wave * 8;
  const float* inN = in + (size_t)nz * CIN * NPIX;
  const float* wb = w + (size_t)oc0 * CIN * KK;  // uniform base -> s_load

  // hoisted staging addresses + masks
  int soff[NQ];
  bool svalid[NQ];
  #pragma unroll
  for (int q = 0; q < NQ; ++q) {
    int id = t + q * 256;
    int row = id / 36, col = id - row * 36;
    int gy = Y0 + row - PAD, gx = X0 + col - PAD;
    svalid[q] = (id < NIN) && gy >= 0 && gy < HW && gx >= 0 && gx < HW && (col < 32 + 2 * PAD);
    soff[q] = gy * HW + gx;
  }

  float acc[8][2][4];
  #pragma unroll
  for (int j = 0; j < 8; ++j)
    #pragma unroll
    for (int py = 0; py < 2; ++py)
      #pragma unroll
      for (int px = 0; px < 4; ++px) acc[j][py][px] = 0.f;

  // prologue: stage ch0 into buf0, prefetch ch1 into regs, barrier
  float vi[NQ];
  #pragma unroll
  for (int q = 0; q < NQ; ++q) vi[q] = svalid[q] ? inN[soff[q]] : 0.f;
  #pragma unroll
  for (int q = 0; q < NQ; ++q) {
    int id = t + q * 256;
    if (id < NIN) sIn[0][id] = vi[q];
  }
  if (CIN > 1) {
    #pragma unroll
    for (int q = 0; q < NQ; ++q) vi[q] = svalid[q] ? inN[NPIX + soff[q]] : 0.f;
  }
  __syncthreads();

  for (int ic = 0; ic < CIN; ++ic) {
    const int cur = ic & 1;
    // write next channel into alternate buffer (prev barrier: its readers done)
    if (ic + 1 < CIN) {
      float* sNxt = sIn[cur ^ 1];
      #pragma unroll
      for (int q = 0; q < NQ; ++q) {
        int id = t + q * 256;
        if (id < NIN) sNxt[id] = vi[q];
      }
    }
    // prefetch channel ic+2 into regs; latency hides under this channel's FMAs
    if (ic + 2 < CIN) {
      const float* src = inN + (size_t)(ic + 2) * NPIX;
      #pragma unroll
      for (int q = 0; q < NQ; ++q) vi[q] = svalid[q] ? src[soff[q]] : 0.f;
    }
    // compute this channel from buf[cur]
    const float* sBase = sIn[cur];
    float rin[RR][8];
    #pragma unroll
    for (int r = 0; r < RR; ++r) {
      const float4 a4 = *reinterpret_cast<const float4*>(&sBase[(y0l + r) * 36 + x0l]);
      const float4 b4 = *reinterpret_cast<const float4*>(&sBase[(y0l + r) * 36 + x0l + 4]);
      rin[r][0] = a4.x; rin[r][1] = a4.y; rin[r][2] = a4.z; rin[r][3] = a4.w;
      rin[r][4] = b4.x; rin[r][5] = b4.y; rin[r][6] = b4.z; rin[r][7] = b4.w;
    }
    #pragma unroll
    for (int j = 0; j < 8; ++j) {
      const float* wp = wb + ((size_t)j * CIN + ic) * KK;  // uniform -> s_load
      float wr[KK];
      #pragma unroll
      for (int k = 0; k < KK; ++k) wr[k] = wp[k];
      #pragma unroll
      for (int ky = 0; ky < K; ++ky)
        #pragma unroll
        for (int kx = 0; kx < K; ++kx) {
          const float wc = wr[ky * K + kx];
          #pragma unroll
          for (int py = 0; py < 2; ++py)
            #pragma unroll
            for (int px = 0; px < 4; ++px)
              acc[j][py][px] = fmaf(rin[py + ky][px + kx], wc, acc[j][py][px]);
        }
    }
    __syncthreads();  // readers of buf[cur] done; writes to buf[cur^1] visible
  }

  float* outN = out + (size_t)nz * 32 * NPIX;
  #pragma unroll
  for (int j = 0; j < 8; ++j) {
    const float sc = sScale[oc0 + j], sh = sShift[oc0 + j];
    #pragma unroll
    for (int py = 0; py < 2; ++py) {
      float4 o;
      o.x = lrelu(acc[j][py][0] * sc + sh);
      o.y = lrelu(acc[j][py][1] * sc + sh);
      o.z = lrelu(acc[j][py][2] * sc + sh);
      o.w = lrelu(acc[j][py][3] * sc + sh);
      *reinterpret_cast<float4*>(
          &outN[(size_t)(oc0 + j) * NPIX + (Y0 + y0l + py) * HW + X0 + x0l]) = o;
    }
  }
}

// ---------------- L4: 32 -> 1, 3x3 pad1, BN4, +residual, lrelu -> feat [40][NPIX] ----------------
// double-buffered LDS, one barrier per channel, hoisted addresses, scalar weights.
__global__ __launch_bounds__(256) void conv4_kernel(const float* __restrict__ in,
                                                    const float* __restrict__ gt1,
                                                    const float* __restrict__ refs,
                                                    const float* __restrict__ w4,
                                                    const float* __restrict__ b4,
                                                    const float* __restrict__ g4,
                                                    const float* __restrict__ be4,
                                                    const float* __restrict__ m4,
                                                    const float* __restrict__ v4,
                                                    float* __restrict__ feat, int i0) {
  __shared__ float sIn[2][34 * 34];
  const int t = threadIdx.x;
  const int nz = blockIdx.z, n = i0 + nz;
  const int X0 = blockIdx.x * 32, Y0 = blockIdx.y * 32;
  const int tx = t & 15, ty = t >> 4;
  const int lx = tx * 2, ly = ty * 2;
  const float* inN = in + (size_t)nz * 32 * NPIX;

  int soff[5];
  bool svalid[5];
  #pragma unroll
  for (int q = 0; q < 5; ++q) {
    int id = t + q * 256;
    int row = id / 34, col = id - row * 34;
    int gy = Y0 + row - 1, gx = X0 + col - 1;
    svalid[q] = (id < 34 * 34) && gy >= 0 && gy < HW && gx >= 0 && gx < HW;
    soff[q] = gy * HW + gx;
  }

  float a[2][2] = {{0.f, 0.f}, {0.f, 0.f}};
  float vi[5];
  #pragma unroll
  for (int q = 0; q < 5; ++q) vi[q] = svalid[q] ? inN[soff[q]] : 0.f;
  #pragma unroll
  for (int q = 0; q < 5; ++q) {
    int id = t + q * 256;
    if (id < 34 * 34) sIn[0][id] = vi[q];
  }
  #pragma unroll
  for (int q = 0; q < 5; ++q) vi[q] = svalid[q] ? inN[NPIX + soff[q]] : 0.f;
  __syncthreads();

  int cur = 0;
  for (int ic = 0; ic < 32; ++ic) {
    const float* sBase = sIn[cur];
    float rin[4][4];
    #pragma unroll
    for (int r = 0; r < 4; ++r) {
      const float2 p0 = *reinterpret_cast<const float2*>(&sBase[(ly + r) * 34 + lx]);
      const float2 p1 = *reinterpret_cast<const float2*>(&sBase[(ly + r) * 34 + lx + 2]);
      rin[r][0] = p0.x; rin[r][1] = p0.y; rin[r][2] = p1.x; rin[r][3] = p1.y;
    }
    if (ic + 1 < 32) {
      float* sNxt = sIn[cur ^ 1];
      #pragma unroll
      for (int q = 0; q < 5; ++q) {
        int id = t + q * 256;
        if (id < 34 * 34) sNxt[id] = vi[q];
      }
    }
    if (ic + 2 < 32) {
      const float* src = inN + (size_t)(ic + 2) * NPIX;
      #pragma unroll
      for (int q = 0; q < 5; ++q) vi[q] = svalid[q] ? src[soff[q]] : 0.f;
    }
    const float* wp = w4 + ic * 9;  // uniform -> s_load
    float wv[9];
    #pragma unroll
    for (int k = 0; k < 9; ++k) wv[k] = wp[k];
    #pragma unroll
    for (int ky = 0; ky < 3; ++ky)
      #pragma unroll
      for (int kx = 0; kx < 3; ++kx) {
        const float wc = wv[ky * 3 + kx];
        a[0][0] = fmaf(rin[ky][kx], wc, a[0][0]);
        a[0][1] = fmaf(rin[ky][kx + 1], wc, a[0][1]);
        a[1][0] = fmaf(rin[ky + 1][kx], wc, a[1][0]);
        a[1][1] = fmaf(rin[ky + 1][kx + 1], wc, a[1][1]);
      }
    __syncthreads();
    cur ^= 1;
  }
  const float inv = g4[0] / sqrtf(v4[0] + 1e-5f);
  const float sh = b4[0] * inv + be4[0] - m4[0] * inv;
  const float* res = (n < 8) ? (gt1 + (size_t)n * NPIX) : (refs + (size_t)(n - 8) * NPIX);
  #pragma unroll
  for (int dy = 0; dy < 2; ++dy)
    #pragma unroll
    for (int dx = 0; dx < 2; ++dx) {
      int px = (Y0 + ly + dy) * HW + X0 + lx + dx;
      float val = a[dy][dx] * inv + sh + res[px];
      feat[(size_t)n * NPIX + px] = lrelu(val);
    }
}

// ---------------- final: diff/min/max/norm/threshold/argmax/collage ----------------
__global__ __launch_bounds__(256) void final_kernel(const float* __restrict__ feat,
                                                    float* __restrict__ outD) {
  int idx = blockIdx.x * 256 + threadIdx.x;  // 8*65536
  int b = idx >> 16, px = idx & 65535;
  float gv = feat[(size_t)b * NPIX + px];
  float tv[4];
  float mn = 1e30f, mx = -1e30f;
  #pragma unroll
  for (int r = 0; r < 4; ++r) {
    float rv = feat[(size_t)(8 + b * 4 + r) * NPIX + px];
    tv[r] = fabsf(gv - rv);
    mn = fminf(mn, tv[r]);
    mx = fmaxf(mx, tv[r]);
  }
  const float denom = mx - mn + 1e-8f;
  float d[4];
  #pragma unroll
  for (int r = 0; r < 4; ++r) {
    float nrm = (tv[r] - mn) / denom;
    nrm = fminf(fmaxf(nrm, 0.1f), 1.0f);
    d[r] = nrm > 0.5f ? nrm : 0.f;
    outD[(size_t)(b * 4 + r) * NPIX + px] = d[r];
  }
  int best = 0;
  float bv = d[0];
  #pragma unroll
  for (int r = 1; r < 4; ++r)
    if (d[r] > bv) { bv = d[r]; best = r; }
  outD[(size_t)32 * NPIX + (size_t)b * NPIX + px] =
      feat[(size_t)(8 + b * 4 + best) * NPIX + px];
}

extern "C" void kernel_launch(void* const* d_in, const int* in_sizes, int n_in,
                              void* d_out, int out_size, void* d_ws, size_t ws_size,
                              hipStream_t stream) {
  const float* gt   = (const float*)d_in[0];
  const float* refs = (const float*)d_in[1];
  const float* w0 = (const float*)d_in[2];
  const float* b0 = (const float*)d_in[3];
  const float* w1 = (const float*)d_in[4];
  const float* b1 = (const float*)d_in[5];
  const float* g1 = (const float*)d_in[6];
  const float* be1 = (const float*)d_in[7];
  const float* m1 = (const float*)d_in[8];
  const float* v1 = (const float*)d_in[9];
  const float* w2 = (const float*)d_in[10];
  const float* b2 = (const float*)d_in[11];
  const float* g2 = (const float*)d_in[12];
  const float* be2 = (const float*)d_in[13];
  const float* m2 = (const float*)d_in[14];
  const float* v2 = (const float*)d_in[15];
  const float* w3 = (const float*)d_in[16];
  const float* b3 = (const float*)d_in[17];
  const float* g3 = (const float*)d_in[18];
  const float* be3 = (const float*)d_in[19];
  const float* m3 = (const float*)d_in[20];
  const float* v3 = (const float*)d_in[21];
  const float* w4 = (const float*)d_in[22];
  const float* b4 = (const float*)d_in[23];
  const float* g4 = (const float*)d_in[24];
  const float* be4 = (const float*)d_in[25];
  const float* m4 = (const float*)d_in[26];
  const float* v4 = (const float*)d_in[27];

  float* ws = (float*)d_ws;
  float* gt1  = ws;                      // 8 * NPIX
  float* feat = gt1 + (size_t)8 * NPIX;  // 40 * NPIX
  float* bufBase = feat + (size_t)40 * NPIX;

  size_t fixedBytes = (size_t)(8 + 40) * NPIX * sizeof(float);
  size_t avail = (ws_size > fixedBytes) ? (ws_size - fixedBytes) : 0;
  size_t perImg = (size_t)2 * 32 * NPIX * sizeof(float);  // bufA + bufB per image
  int maxC = (int)(avail / perImg);
  static const int divs[8] = {40, 20, 10, 8, 5, 4, 2, 1};
  int chunk = 1;
  for (int i = 0; i < 8; ++i)
    if (divs[i] <= maxC) { chunk = divs[i]; break; }

  float* bufA = bufBase;
  float* bufB = bufA + (size_t)chunk * 32 * NPIX;

  conv0_kernel<<<2048, 256, 0, stream>>>(gt, w0, b0, gt1);

  for (int i0 = 0; i0 < 40; i0 += chunk) {
    conv1_kernel<<<dim3(8, 8, chunk), 256, 0, stream>>>(gt1, refs, w1, b1, g1, be1, m1, v1,
                                                        bufA, i0);
    convT5_kernel<16, 3><<<dim3(8, 16, chunk), 256, 0, stream>>>(bufA, w2, b2, g2, be2, m2, v2,
                                                                 bufB);
    convT5_kernel<32, 5><<<dim3(8, 16, chunk), 256, 0, stream>>>(bufB, w3, b3, g3, be3, m3, v3,
                                                                 bufA);
    conv4_kernel<<<dim3(8, 8, chunk), 256, 0, stream>>>(bufA, gt1, refs, w4, b4, g4, be4, m4,
                                                        v4, feat, i0);
  }

  final_kernel<<<2048, 256, 0, stream>>>(feat, (float*)d_out);
}